// Round 4
// baseline (3198.946 us; speedup 1.0000x reference)
//
#include <hip/hip_runtime.h>
#include <math.h>

// ---------------------------------------------------------------------------
// HybridBERT4RecGNN forward on MI355X (gfx950), round 4.
//
// R3 -> R4: seq_transformer occupancy was the limiter (2 blocks/CU from 65 KB
// LDS x 4 waves = 2 waves/SIMD; VALUBusy 58% @ 22% occupancy). Same LDS
// footprint, but 512 threads/block (8 waves, ~6-7 rows each, strided row map
// s = wid + 8*ir) -> 4 waves/SIMD, halved per-wave dependent chains.
// GNN path unchanged from R3 (CSR build + gather).
// ---------------------------------------------------------------------------

#define SD   64   // model dim
#define SS   50   // seq len (MAXLEN)
#define DFF  256
#define NBLK 2
#define PX   68   // pitch for float4-broadcastable row buffers (multiple of 4)
#define PK   65   // pitch for transposed-K / V buffers (odd -> conflict-free cols)
#define NW   8    // waves per block
#define RPW  7    // max rows per wave (ceil(50/8))

__device__ __forceinline__ float wred_sum(float v) {
#pragma unroll
  for (int o = 32; o > 0; o >>= 1) v += __shfl_xor(v, o, 64);
  return v;
}
// fused sum of (a, b) in one butterfly: halves the dependent-stage count
__device__ __forceinline__ float2 wred_sum2(float a, float b) {
#pragma unroll
  for (int o = 32; o > 0; o >>= 1) {
    a += __shfl_xor(a, o, 64);
    b += __shfl_xor(b, o, 64);
  }
  return make_float2(a, b);
}
__device__ __forceinline__ float gelu_tanh(float x) {
  // tanh via hardware v_exp_f32: tanh(u) = sign(u) * (1-e^{-2|u|})/(1+e^{-2|u|})
  float u = 0.7978845608028654f * (x + 0.044715f * x * x * x);
  float a = fabsf(u);
  float e = __expf(-2.f * a);
  float th = copysignf((1.f - e) / (1.f + e), u);
  return 0.5f * x * (1.0f + th);
}

// Load one weight column (this lane's output dim) into registers.
template <int LDW>
__device__ __forceinline__ void load_wcol(const float* __restrict__ W, int lane,
                                          float wreg[SD]) {
#pragma unroll
  for (int k = 0; k < SD; ++k) wreg[k] = W[k * LDW + lane];
}

// dot(in_row[0:64], wreg[0:64]); in_row is an LDS row (16B aligned) -> the
// float4 reads are same-address wave broadcasts (conflict-free).
__device__ __forceinline__ float dot_wreg(const float* in_row,
                                          const float wreg[SD]) {
  float ax = 0.f, ay = 0.f, az = 0.f, aw = 0.f;
#pragma unroll
  for (int k4 = 0; k4 < 16; ++k4) {
    float4 xv = *(const float4*)(in_row + 4 * k4);
    ax += xv.x * wreg[4 * k4 + 0];
    ay += xv.y * wreg[4 * k4 + 1];
    az += xv.z * wreg[4 * k4 + 2];
    aw += xv.w * wreg[4 * k4 + 3];
  }
  return (ax + ay) + (az + aw);
}

// ---------------------------------------------------------------------------
// GNN path A (preferred): CSR build + gather
// ---------------------------------------------------------------------------
__global__ void gnn_hist(const int* __restrict__ dst, int* __restrict__ cnt, int E) {
  int e = blockIdx.x * blockDim.x + threadIdx.x;
  if (e < E) atomicAdd(&cnt[dst[e]], 1);
}

// per-1024-chunk sums (cnt is zero-padded to NCH*1024)
__global__ void gnn_chunk_sums(const int* __restrict__ cnt, int* __restrict__ bsum) {
  __shared__ int ssum;
  if (threadIdx.x == 0) ssum = 0;
  __syncthreads();
  int base = blockIdx.x * 1024 + threadIdx.x * 4;
  int s = cnt[base] + cnt[base + 1] + cnt[base + 2] + cnt[base + 3];
#pragma unroll
  for (int o = 32; o > 0; o >>= 1) s += __shfl_xor(s, o, 64);
  if ((threadIdx.x & 63) == 0) atomicAdd(&ssum, s);
  __syncthreads();
  if (threadIdx.x == 0) bsum[blockIdx.x] = ssum;
}

// exclusive scan of bsum in place (NCH <= 128)
__global__ void gnn_scan_bsum(int* __restrict__ bsum, int nch) {
  __shared__ int sb[128];
  int t = threadIdx.x;
  if (t < nch) sb[t] = bsum[t];
  __syncthreads();
  if (t == 0) {
    int a = 0;
    for (int i = 0; i < nch; ++i) { int v = sb[i]; sb[i] = a; a += v; }
  }
  __syncthreads();
  if (t < nch) bsum[t] = sb[t];
}

// per-chunk exclusive scan -> row_ptr (N+1) and write cursor wp (N)
__global__ void gnn_chunk_scan(const int* __restrict__ cnt, const int* __restrict__ bofs,
                               int* __restrict__ rp, int* __restrict__ wp, int Nn) {
  __shared__ int wsum[4];
  int t = threadIdx.x, lane = t & 63, wv = t >> 6;
  int base = blockIdx.x * 1024 + t * 4;
  int c0 = cnt[base], c1 = cnt[base + 1], c2 = cnt[base + 2], c3 = cnt[base + 3];
  int s = c0 + c1 + c2 + c3;
  int x = s;  // inclusive wave scan
#pragma unroll
  for (int o = 1; o < 64; o <<= 1) {
    int y = __shfl_up(x, o, 64);
    if (lane >= o) x += y;
  }
  if (lane == 63) wsum[wv] = x;
  __syncthreads();
  int wo = 0;
#pragma unroll
  for (int i = 0; i < 4; ++i) if (i < wv) wo += wsum[i];
  int excl = bofs[blockIdx.x] + wo + (x - s);
  int p[4];
  p[0] = excl; p[1] = p[0] + c0; p[2] = p[1] + c1; p[3] = p[2] + c2;
#pragma unroll
  for (int j = 0; j < 4; ++j) {
    int idx = base + j;
    if (idx <= Nn) rp[idx] = p[j];
    if (idx < Nn) wp[idx] = p[j];
  }
}

__global__ void gnn_build(const int* __restrict__ src, const int* __restrict__ dst,
                          const float* __restrict__ ew, int* __restrict__ wp,
                          int* __restrict__ es, float* __restrict__ ewt, int E) {
  int e = blockIdx.x * blockDim.x + threadIdx.x;
  if (e >= E) return;
  int pos = atomicAdd(&wp[dst[e]], 1);
  es[pos] = src[e];
  ewt[pos] = ew[e];
}

// wave per dst node; lane = dim; regular accumulate, no atomics
__global__ void gnn_gather(const float* __restrict__ xin, const int* __restrict__ rp,
                           const int* __restrict__ es, const float* __restrict__ ewt,
                           float* __restrict__ xout, int Nn) {
  int n = blockIdx.x * 4 + (threadIdx.x >> 6);
  int lane = threadIdx.x & 63;
  if (n >= Nn) return;
  int beg = rp[n], end = rp[n + 1];
  float acc = 0.f;
  int e = beg;
  for (; e + 4 <= end; e += 4) {
    int s0 = es[e], s1 = es[e + 1], s2 = es[e + 2], s3 = es[e + 3];
    float w0 = ewt[e], w1 = ewt[e + 1], w2 = ewt[e + 2], w3 = ewt[e + 3];
    float x0 = xin[(size_t)s0 * SD + lane];
    float x1 = xin[(size_t)s1 * SD + lane];
    float x2 = xin[(size_t)s2 * SD + lane];
    float x3 = xin[(size_t)s3 * SD + lane];
    acc += x0 * w0 + x1 * w1 + x2 * w2 + x3 * w3;
  }
  for (; e < end; ++e) acc += xin[(size_t)es[e] * SD + lane] * ewt[e];
  xout[(size_t)n * SD + lane] = acc;
}

// ---------------------------------------------------------------------------
// GNN path B (fallback, R2): atomic scatter
// ---------------------------------------------------------------------------
__global__ void gnn_scatter(const float* __restrict__ xin,
                            const int* __restrict__ src,
                            const int* __restrict__ dst,
                            const float* __restrict__ ew,
                            float* __restrict__ xout, int E) {
  int gid = blockIdx.x * blockDim.x + threadIdx.x;
  int e = gid >> 6;
  int d = gid & 63;
  if (e >= E) return;
  atomicAdd(&xout[(size_t)dst[e] * SD + d], xin[(size_t)src[e] * SD + d] * ew[e]);
}

// ---------------------------------------------------------------------------
// Per-sequence fused kernel. 512 threads = 8 waves; wave w owns rows
// s = w + 8*ir (ir < 7, s < 50); lane = feature/column index.
// LDS: (3400 + 3400 + 4160 + 5200)*4 + 200 = 64,840 B  (2 blocks/CU,
// 16 waves/CU = 4 waves/SIMD).
// ---------------------------------------------------------------------------
__global__ __launch_bounds__(512, 4)
void seq_transformer(const int* __restrict__ seq, const int* __restrict__ lengths,
                     const float* __restrict__ bert, const float* __restrict__ gnn,
                     const float* __restrict__ g1x, const float* __restrict__ g2x,
                     const float* __restrict__ pw, const float* __restrict__ pbias,
                     const float* __restrict__ pos,
                     const float* __restrict__ wq, const float* __restrict__ wk,
                     const float* __restrict__ wv, const float* __restrict__ wo,
                     const float* __restrict__ w1, const float* __restrict__ b1,
                     const float* __restrict__ w2, const float* __restrict__ b2,
                     const float* __restrict__ ln1g, const float* __restrict__ ln1b,
                     const float* __restrict__ ln2g, const float* __restrict__ ln2b,
                     const float* __restrict__ lnfg, const float* __restrict__ lnfb,
                     float* __restrict__ out) {
  __shared__ float xs[SS * PX];        // current hidden state, pitch 68
  __shared__ float bufA[SS * PX];      // q(p68) / v(p65) / ffn-h(p68) / gnn tmp
  __shared__ float bufB[SD * PK];      // K^T (64 x 50, p65)  /  ctx (p68)
  __shared__ float scw[2 * SS * 52];   // attention scores/weights [2][50][52]
  __shared__ int   sidx[SS];

  const int t = threadIdx.x;
  const int lane = t & 63;
  const int wid = t >> 6;
  const int b = blockIdx.x;

  if (t < SS) sidx[t] = seq[b * SS + t];
  __syncthreads();

  const int len = lengths[b];
  const float alpha = (len <= 10) ? 0.3f : ((len >= 50) ? 0.7f : 0.5f);
  const float one_m_alpha = 1.0f - alpha;

  float wreg[SD];  // register-resident weight column, reused across rows

  // ---- phase 0a: averaged GNN rows for this sequence's tokens -> bufA
#pragma unroll
  for (int ir = 0; ir < RPW; ++ir) {
    int s = wid + NW * ir;
    if (s < SS) {
      size_t base = (size_t)sidx[s] * SD + lane;
      bufA[s * PX + lane] = (gnn[base] + g1x[base] + g2x[base]) * (1.0f / 3.0f);
    }
  }
  __syncthreads();

  // ---- phase 0b: gnn projection + discrete-alpha blend + pos emb -> xs
  load_wcol<SD>(pw, lane, wreg);
  {
    float pbv = pbias[lane];
#pragma unroll
    for (int ir = 0; ir < RPW; ++ir) {
      int s = wid + NW * ir;
      if (s < SS) {
        float g = dot_wreg(&bufA[s * PX], wreg) + pbv;
        size_t base = (size_t)sidx[s] * SD + lane;
        xs[s * PX + lane] = alpha * bert[base] + one_m_alpha * g + pos[s * SD + lane];
      }
    }
  }
  __syncthreads();

  const float inv_sqrt_dh = 0.17677669529663687f;  // 1/sqrt(32)

#pragma unroll 1
  for (int blk = 0; blk < NBLK; ++blk) {
    const float* Wq = wq + blk * SD * SD;
    const float* Wk = wk + blk * SD * SD;
    const float* Wv = wv + blk * SD * SD;
    const float* Wo = wo + blk * SD * SD;
    const float* W1 = w1 + blk * SD * DFF;
    const float* B1 = b1 + blk * DFF;
    const float* W2 = w2 + blk * DFF * SD;
    const float* B2 = b2 + blk * SD;

    // ---- Q -> bufA (p68)
    load_wcol<SD>(Wq, lane, wreg);
#pragma unroll
    for (int ir = 0; ir < RPW; ++ir) {
      int s = wid + NW * ir;
      if (s < SS) bufA[s * PX + lane] = dot_wreg(&xs[s * PX], wreg);
    }
    // ---- K^T -> bufB (p65, transposed write, conflict-free)
    load_wcol<SD>(Wk, lane, wreg);
#pragma unroll
    for (int ir = 0; ir < RPW; ++ir) {
      int s = wid + NW * ir;
      if (s < SS) bufB[lane * PK + s] = dot_wreg(&xs[s * PX], wreg);
    }
    __syncthreads();

    // ---- scores: wave rows = sq, lane = sk. K column held in registers,
    //      reused across the wave's query rows.
    {
      const int sk = lane;
      const bool skv = (sk < SS);
      const bool kmask = skv && (sidx[sk] != 0);
#pragma unroll 1
      for (int h = 0; h < 2; ++h) {
        float kr[32];
#pragma unroll
        for (int dh = 0; dh < 32; ++dh) kr[dh] = bufB[(h * 32 + dh) * PK + sk];
#pragma unroll
        for (int ir = 0; ir < RPW; ++ir) {
          int sq = wid + NW * ir;
          if (sq < SS) {
            float ax = 0.f, ay = 0.f, az = 0.f, aw = 0.f;
#pragma unroll
            for (int j = 0; j < 8; ++j) {
              float4 qv = *(const float4*)&bufA[sq * PX + h * 32 + 4 * j];
              ax += qv.x * kr[4 * j + 0];
              ay += qv.y * kr[4 * j + 1];
              az += qv.z * kr[4 * j + 2];
              aw += qv.w * kr[4 * j + 3];
            }
            float sc = ((ax + ay) + (az + aw)) * inv_sqrt_dh;
            if (skv) scw[(h * SS + sq) * 52 + sk] = kmask ? sc : -1e9f;
          }
        }
      }
    }
    __syncthreads();

    // ---- softmax: wave per (h,sq) row, lane = sk; rows in independent pairs
    {
      int r = wid;
#pragma unroll 1
      for (; r + NW < 2 * SS; r += 2 * NW) {
        float v0 = (lane < SS) ? scw[r * 52 + lane] : -1e30f;
        float v1 = (lane < SS) ? scw[(r + NW) * 52 + lane] : -1e30f;
        float m0 = v0, m1 = v1;
#pragma unroll
        for (int o = 32; o > 0; o >>= 1) {
          m0 = fmaxf(m0, __shfl_xor(m0, o, 64));
          m1 = fmaxf(m1, __shfl_xor(m1, o, 64));
        }
        float e0 = (lane < SS) ? __expf(v0 - m0) : 0.f;
        float e1 = (lane < SS) ? __expf(v1 - m1) : 0.f;
        float2 sm = wred_sum2(e0, e1);
        if (lane < 52) {
          scw[r * 52 + lane] = e0 / sm.x;        // cols 50,51 zeroed for f4 ctx
          scw[(r + NW) * 52 + lane] = e1 / sm.y;
        }
      }
      if (r < 2 * SS) {
        float v = (lane < SS) ? scw[r * 52 + lane] : -1e30f;
        float mx = v;
#pragma unroll
        for (int o = 32; o > 0; o >>= 1) mx = fmaxf(mx, __shfl_xor(mx, o, 64));
        float e = (lane < SS) ? __expf(v - mx) : 0.f;
        float sm = wred_sum(e);
        if (lane < 52) scw[r * 52 + lane] = e / sm;
      }
    }
    __syncthreads();

    // ---- V -> bufA (p65; overwrites consumed Q)
    load_wcol<SD>(Wv, lane, wreg);
#pragma unroll
    for (int ir = 0; ir < RPW; ++ir) {
      int s = wid + NW * ir;
      if (s < SS) bufA[s * PK + lane] = dot_wreg(&xs[s * PX], wreg);
    }
    __syncthreads();

    // ---- ctx = attn @ V -> bufB (p68; overwrites consumed K^T).
    //      attn cols 50,51 are exact zeros; stale v-rows 50,51 are finite.
#pragma unroll
    for (int ir = 0; ir < RPW; ++ir) {
      int sq = wid + NW * ir;
      if (sq < SS) {
        const int hb = (lane >> 5) * SS * 52;
        float ax = 0.f, ay = 0.f, az = 0.f, aw = 0.f;
#pragma unroll
        for (int j = 0; j < 13; ++j) {
          float4 av = *(const float4*)&scw[hb + sq * 52 + 4 * j];
          ax += av.x * bufA[(4 * j + 0) * PK + lane];
          ay += av.y * bufA[(4 * j + 1) * PK + lane];
          az += av.z * bufA[(4 * j + 2) * PK + lane];
          aw += av.w * bufA[(4 * j + 3) * PK + lane];
        }
        bufB[sq * PX + lane] = (ax + ay) + (az + aw);
      }
    }
    __syncthreads();

    // ---- O-projection + residual + LN1 -> xs
    load_wcol<SD>(Wo, lane, wreg);
    {
      float gv = ln1g[blk * SD + lane], bv = ln1b[blk * SD + lane];
#pragma unroll
      for (int ir = 0; ir < RPW; ++ir) {
        int s = wid + NW * ir;
        if (s < SS) {
          float o = dot_wreg(&bufB[s * PX], wreg);
          float val = xs[s * PX + lane] + o;
          float2 ss = wred_sum2(val, val * val);
          float m = ss.x * (1.f / 64);
          float var = fmaxf(ss.y * (1.f / 64) - m * m, 0.f);
          float rs = rsqrtf(var + 1e-5f);
          xs[s * PX + lane] = (val - m) * rs * gv + bv;
        }
      }
    }
    __syncthreads();

    // ---- FFN: 4 chunks of 64 hidden dims; h staged in bufA, out accumulated
    //      in registers across chunks.
    float acc2[RPW];
#pragma unroll
    for (int ir = 0; ir < RPW; ++ir) acc2[ir] = 0.f;
#pragma unroll 1
    for (int c = 0; c < 4; ++c) {
      // W1 chunk: columns c*64+lane, rows 0..63
      load_wcol<DFF>(W1 + c * 64, lane, wreg);
      float b1v = B1[c * 64 + lane];
#pragma unroll
      for (int ir = 0; ir < RPW; ++ir) {
        int s = wid + NW * ir;
        if (s < SS) {
          float h = b1v + dot_wreg(&xs[s * PX], wreg);
          bufA[s * PX + lane] = gelu_tanh(h);
        }
      }
      __syncthreads();
      // W2 chunk: rows c*64..c*64+63, column lane
      load_wcol<SD>(W2 + c * 64 * SD, lane, wreg);
#pragma unroll
      for (int ir = 0; ir < RPW; ++ir) {
        int s = wid + NW * ir;
        if (s < SS) acc2[ir] += dot_wreg(&bufA[s * PX], wreg);
      }
      __syncthreads();
    }

    // ---- residual + LN2 -> xs
    {
      float gv = ln2g[blk * SD + lane], bv = ln2b[blk * SD + lane];
      float b2v = B2[lane];
#pragma unroll
      for (int ir = 0; ir < RPW; ++ir) {
        int s = wid + NW * ir;
        if (s < SS) {
          float val = xs[s * PX + lane] + acc2[ir] + b2v;
          float2 ss = wred_sum2(val, val * val);
          float m = ss.x * (1.f / 64);
          float var = fmaxf(ss.y * (1.f / 64) - m * m, 0.f);
          float rs = rsqrtf(var + 1e-5f);
          xs[s * PX + lane] = (val - m) * rs * gv + bv;
        }
      }
    }
    __syncthreads();
  }

  // ---- final LN + gather row (lengths-1)
  if (wid == 0) {
    int sl = len - 1;
    float val = xs[sl * PX + lane];
    float2 ss = wred_sum2(val, val * val);
    float m = ss.x * (1.f / 64);
    float var = fmaxf(ss.y * (1.f / 64) - m * m, 0.f);
    float rs = rsqrtf(var + 1e-5f);
    out[b * SD + lane] = (val - m) * rs * lnfg[lane] + lnfb[lane];
  }
}

// ---------------------------------------------------------------------------
extern "C" void kernel_launch(void* const* d_in, const int* in_sizes, int n_in,
                              void* d_out, int out_size, void* d_ws, size_t ws_size,
                              hipStream_t stream) {
  const int*   seq   = (const int*)d_in[0];
  const int*   lens  = (const int*)d_in[1];
  const int*   ei    = (const int*)d_in[2];
  const float* ew    = (const float*)d_in[3];
  const float* bert  = (const float*)d_in[4];
  const float* gnn   = (const float*)d_in[5];
  const float* pw    = (const float*)d_in[6];
  const float* pb    = (const float*)d_in[7];
  const float* pos   = (const float*)d_in[8];
  const float* wq    = (const float*)d_in[9];
  const float* wk    = (const float*)d_in[10];
  const float* wv    = (const float*)d_in[11];
  const float* wo    = (const float*)d_in[12];
  const float* w1    = (const float*)d_in[13];
  const float* b1    = (const float*)d_in[14];
  const float* w2    = (const float*)d_in[15];
  const float* b2    = (const float*)d_in[16];
  const float* ln1g  = (const float*)d_in[17];
  const float* ln1b  = (const float*)d_in[18];
  const float* ln2g  = (const float*)d_in[19];
  const float* ln2b  = (const float*)d_in[20];
  const float* lnfg  = (const float*)d_in[21];
  const float* lnfb  = (const float*)d_in[22];
  float* out = (float*)d_out;

  const int E = in_sizes[2] / 2;          // 1,000,000
  const int B = in_sizes[0] / SS;         // 1024
  const int N = in_sizes[4] / SD;         // 100,001

  const int*   esrc = ei;
  const int*   edst = ei + E;

  // ---- workspace layout
  float* g1x = (float*)d_ws;                       // N x 64
  float* g2x = g1x + (size_t)N * SD;               // N x 64
  const int NCH = (N + 1023) >> 10;                // scan chunks of 1024
  const int PADN = NCH << 10;                      // padded count array size
  int*   cnt  = (int*)(g2x + (size_t)N * SD);      // PADN
  int*   bsum = cnt + PADN;                        // NCH (<=128)
  int*   rp   = bsum + 128;                        // N+1
  int*   wp   = rp + (N + 1);                      // N
  int*   es   = wp + N;                            // E
  float* ewt  = (float*)(es + E);                  // E
  size_t need = (size_t)((char*)(ewt + E) - (char*)d_ws);

  if (ws_size >= need && NCH <= 128) {
    // ---- CSR build + gather (no atomics in the heavy passes)
    hipMemsetAsync(cnt, 0, (size_t)PADN * sizeof(int), stream);
    const int gb = (E + 255) / 256;
    gnn_hist<<<gb, 256, 0, stream>>>(edst, cnt, E);
    gnn_chunk_sums<<<NCH, 256, 0, stream>>>(cnt, bsum);
    gnn_scan_bsum<<<1, 128, 0, stream>>>(bsum, NCH);
    gnn_chunk_scan<<<NCH, 256, 0, stream>>>(cnt, bsum, rp, wp, N);
    gnn_build<<<gb, 256, 0, stream>>>(esrc, edst, ew, wp, es, ewt, E);
    const int nb = (N + 3) / 4;
    gnn_gather<<<nb, 256, 0, stream>>>(gnn, rp, es, ewt, g1x, N);
    gnn_gather<<<nb, 256, 0, stream>>>(g1x, rp, es, ewt, g2x, N);
  } else {
    // ---- fallback: R2 atomic scatter
    hipMemsetAsync(g1x, 0, (size_t)2 * N * SD * sizeof(float), stream);
    const long total = (long)E * 64;
    const int sblocks = (int)((total + 255) / 256);
    gnn_scatter<<<sblocks, 256, 0, stream>>>(gnn, esrc, edst, ew, g1x, E);
    gnn_scatter<<<sblocks, 256, 0, stream>>>(g1x, esrc, edst, ew, g2x, E);
  }

  seq_transformer<<<B, 512, 0, stream>>>(
      seq, lens, bert, gnn, g1x, g2x, pw, pb, pos,
      wq, wk, wv, wo, w1, b1, w2, b2,
      ln1g, ln1b, ln2g, ln2b, lnfg, lnfb, out);
}

// Round 5
// 749.011 us; speedup vs baseline: 4.2709x; 4.2709x over previous
//
#include <hip/hip_runtime.h>
#include <math.h>

// ---------------------------------------------------------------------------
// HybridBERT4RecGNN forward on MI355X (gfx950), round 5.
//
// R4 post-mortem: __launch_bounds__(512,4) caps VGPR at 128; wreg[64] spilled
// to scratch (VGPR_Count=64, 9.3 GB of HBM spill traffic, 6x regression).
// R5: keep 512 threads / 8 waves (44% occupancy), but split-k the weight
// column: wreg[32] per half (#pragma unroll 1 across halves -> one live
// array), per-row partial acc[7] in registers. Peak regs ~90 < 128: no spill.
// GNN path unchanged (CSR build + gather).
// ---------------------------------------------------------------------------

#define SD   64   // model dim
#define SS   50   // seq len (MAXLEN)
#define DFF  256
#define NBLK 2
#define PX   68   // pitch for float4-broadcastable row buffers (multiple of 4)
#define PK   65   // pitch for transposed-K / V buffers (odd -> conflict-free cols)
#define NW   8    // waves per block
#define RPW  7    // max rows per wave (ceil(50/8))

__device__ __forceinline__ float wred_sum(float v) {
#pragma unroll
  for (int o = 32; o > 0; o >>= 1) v += __shfl_xor(v, o, 64);
  return v;
}
// fused sum of (a, b) in one butterfly
__device__ __forceinline__ float2 wred_sum2(float a, float b) {
#pragma unroll
  for (int o = 32; o > 0; o >>= 1) {
    a += __shfl_xor(a, o, 64);
    b += __shfl_xor(b, o, 64);
  }
  return make_float2(a, b);
}
__device__ __forceinline__ float gelu_tanh(float x) {
  // tanh via hardware v_exp_f32
  float u = 0.7978845608028654f * (x + 0.044715f * x * x * x);
  float a = fabsf(u);
  float e = __expf(-2.f * a);
  float th = copysignf((1.f - e) / (1.f + e), u);
  return 0.5f * x * (1.0f + th);
}

// Load 32 consecutive k-rows of this lane's weight column.
template <int LDW>
__device__ __forceinline__ void load_wcol32(const float* __restrict__ W, int lane,
                                            float wreg[32]) {
#pragma unroll
  for (int k = 0; k < 32; ++k) wreg[k] = W[k * LDW + lane];
}

// dot(in_row[0:32], wreg[0:32]); in_row is 16B-aligned LDS -> float4
// same-address broadcasts (conflict-free).
__device__ __forceinline__ float dot32(const float* in_row, const float wreg[32]) {
  float ax = 0.f, ay = 0.f, az = 0.f, aw = 0.f;
#pragma unroll
  for (int k4 = 0; k4 < 8; ++k4) {
    float4 xv = *(const float4*)(in_row + 4 * k4);
    ax += xv.x * wreg[4 * k4 + 0];
    ay += xv.y * wreg[4 * k4 + 1];
    az += xv.z * wreg[4 * k4 + 2];
    aw += xv.w * wreg[4 * k4 + 3];
  }
  return (ax + ay) + (az + aw);
}

// 64-k projection for this wave's rows (input rows at pitch PX in `in`),
// split into two 32-k halves so only one wreg[32] is live at a time.
// Result in acc[RPW].
template <int LDW>
__device__ __forceinline__ void proj_rows(const float* in, const float* __restrict__ W,
                                          int lane, int wid, float acc[RPW]) {
#pragma unroll
  for (int ir = 0; ir < RPW; ++ir) acc[ir] = 0.f;
#pragma unroll 1
  for (int kh = 0; kh < 2; ++kh) {
    float wreg[32];
    load_wcol32<LDW>(W + kh * 32 * LDW, lane, wreg);
#pragma unroll
    for (int ir = 0; ir < RPW; ++ir) {
      int s = wid + NW * ir;
      if (s < SS) acc[ir] += dot32(in + s * PX + kh * 32, wreg);
    }
  }
}

// ---------------------------------------------------------------------------
// GNN path A (preferred): CSR build + gather
// ---------------------------------------------------------------------------
__global__ void gnn_hist(const int* __restrict__ dst, int* __restrict__ cnt, int E) {
  int e = blockIdx.x * blockDim.x + threadIdx.x;
  if (e < E) atomicAdd(&cnt[dst[e]], 1);
}

__global__ void gnn_chunk_sums(const int* __restrict__ cnt, int* __restrict__ bsum) {
  __shared__ int ssum;
  if (threadIdx.x == 0) ssum = 0;
  __syncthreads();
  int base = blockIdx.x * 1024 + threadIdx.x * 4;
  int s = cnt[base] + cnt[base + 1] + cnt[base + 2] + cnt[base + 3];
#pragma unroll
  for (int o = 32; o > 0; o >>= 1) s += __shfl_xor(s, o, 64);
  if ((threadIdx.x & 63) == 0) atomicAdd(&ssum, s);
  __syncthreads();
  if (threadIdx.x == 0) bsum[blockIdx.x] = ssum;
}

__global__ void gnn_scan_bsum(int* __restrict__ bsum, int nch) {
  __shared__ int sb[128];
  int t = threadIdx.x;
  if (t < nch) sb[t] = bsum[t];
  __syncthreads();
  if (t == 0) {
    int a = 0;
    for (int i = 0; i < nch; ++i) { int v = sb[i]; sb[i] = a; a += v; }
  }
  __syncthreads();
  if (t < nch) bsum[t] = sb[t];
}

__global__ void gnn_chunk_scan(const int* __restrict__ cnt, const int* __restrict__ bofs,
                               int* __restrict__ rp, int* __restrict__ wp, int Nn) {
  __shared__ int wsum[4];
  int t = threadIdx.x, lane = t & 63, wv = t >> 6;
  int base = blockIdx.x * 1024 + t * 4;
  int c0 = cnt[base], c1 = cnt[base + 1], c2 = cnt[base + 2], c3 = cnt[base + 3];
  int s = c0 + c1 + c2 + c3;
  int x = s;  // inclusive wave scan
#pragma unroll
  for (int o = 1; o < 64; o <<= 1) {
    int y = __shfl_up(x, o, 64);
    if (lane >= o) x += y;
  }
  if (lane == 63) wsum[wv] = x;
  __syncthreads();
  int wo = 0;
#pragma unroll
  for (int i = 0; i < 4; ++i) if (i < wv) wo += wsum[i];
  int excl = bofs[blockIdx.x] + wo + (x - s);
  int p[4];
  p[0] = excl; p[1] = p[0] + c0; p[2] = p[1] + c1; p[3] = p[2] + c2;
#pragma unroll
  for (int j = 0; j < 4; ++j) {
    int idx = base + j;
    if (idx <= Nn) rp[idx] = p[j];
    if (idx < Nn) wp[idx] = p[j];
  }
}

__global__ void gnn_build(const int* __restrict__ src, const int* __restrict__ dst,
                          const float* __restrict__ ew, int* __restrict__ wp,
                          int* __restrict__ es, float* __restrict__ ewt, int E) {
  int e = blockIdx.x * blockDim.x + threadIdx.x;
  if (e >= E) return;
  int pos = atomicAdd(&wp[dst[e]], 1);
  es[pos] = src[e];
  ewt[pos] = ew[e];
}

__global__ void gnn_gather(const float* __restrict__ xin, const int* __restrict__ rp,
                           const int* __restrict__ es, const float* __restrict__ ewt,
                           float* __restrict__ xout, int Nn) {
  int n = blockIdx.x * 4 + (threadIdx.x >> 6);
  int lane = threadIdx.x & 63;
  if (n >= Nn) return;
  int beg = rp[n], end = rp[n + 1];
  float acc = 0.f;
  int e = beg;
  for (; e + 4 <= end; e += 4) {
    int s0 = es[e], s1 = es[e + 1], s2 = es[e + 2], s3 = es[e + 3];
    float w0 = ewt[e], w1 = ewt[e + 1], w2 = ewt[e + 2], w3 = ewt[e + 3];
    float x0 = xin[(size_t)s0 * SD + lane];
    float x1 = xin[(size_t)s1 * SD + lane];
    float x2 = xin[(size_t)s2 * SD + lane];
    float x3 = xin[(size_t)s3 * SD + lane];
    acc += x0 * w0 + x1 * w1 + x2 * w2 + x3 * w3;
  }
  for (; e < end; ++e) acc += xin[(size_t)es[e] * SD + lane] * ewt[e];
  xout[(size_t)n * SD + lane] = acc;
}

// ---------------------------------------------------------------------------
// GNN path B (fallback): atomic scatter
// ---------------------------------------------------------------------------
__global__ void gnn_scatter(const float* __restrict__ xin,
                            const int* __restrict__ src,
                            const int* __restrict__ dst,
                            const float* __restrict__ ew,
                            float* __restrict__ xout, int E) {
  int gid = blockIdx.x * blockDim.x + threadIdx.x;
  int e = gid >> 6;
  int d = gid & 63;
  if (e >= E) return;
  atomicAdd(&xout[(size_t)dst[e] * SD + d], xin[(size_t)src[e] * SD + d] * ew[e]);
}

// ---------------------------------------------------------------------------
// Per-sequence fused kernel. 512 threads = 8 waves; wave w owns rows
// s = w + 8*ir (ir < 7, s < 50); lane = feature/column index.
// LDS 64,840 B -> 2 blocks/CU = 16 waves/CU = 4 waves/SIMD.
// ---------------------------------------------------------------------------
__global__ __launch_bounds__(512, 4)
void seq_transformer(const int* __restrict__ seq, const int* __restrict__ lengths,
                     const float* __restrict__ bert, const float* __restrict__ gnn,
                     const float* __restrict__ g1x, const float* __restrict__ g2x,
                     const float* __restrict__ pw, const float* __restrict__ pbias,
                     const float* __restrict__ pos,
                     const float* __restrict__ wq, const float* __restrict__ wk,
                     const float* __restrict__ wv, const float* __restrict__ wo,
                     const float* __restrict__ w1, const float* __restrict__ b1,
                     const float* __restrict__ w2, const float* __restrict__ b2,
                     const float* __restrict__ ln1g, const float* __restrict__ ln1b,
                     const float* __restrict__ ln2g, const float* __restrict__ ln2b,
                     const float* __restrict__ lnfg, const float* __restrict__ lnfb,
                     float* __restrict__ out) {
  __shared__ float xs[SS * PX];        // current hidden state, pitch 68
  __shared__ float bufA[SS * PX];      // q(p68) / v(p65) / ffn-h(p68) / gnn tmp
  __shared__ float bufB[SD * PK];      // K^T (64 x 50, p65)  /  ctx (p68)
  __shared__ float scw[2 * SS * 52];   // attention scores/weights [2][50][52]
  __shared__ int   sidx[SS];

  const int t = threadIdx.x;
  const int lane = t & 63;
  const int wid = t >> 6;
  const int b = blockIdx.x;

  if (t < SS) sidx[t] = seq[b * SS + t];
  __syncthreads();

  const int len = lengths[b];
  const float alpha = (len <= 10) ? 0.3f : ((len >= 50) ? 0.7f : 0.5f);
  const float one_m_alpha = 1.0f - alpha;

  float acc[RPW];

  // ---- phase 0a: averaged GNN rows for this sequence's tokens -> bufA
#pragma unroll
  for (int ir = 0; ir < RPW; ++ir) {
    int s = wid + NW * ir;
    if (s < SS) {
      size_t base = (size_t)sidx[s] * SD + lane;
      bufA[s * PX + lane] = (gnn[base] + g1x[base] + g2x[base]) * (1.0f / 3.0f);
    }
  }
  __syncthreads();

  // ---- phase 0b: gnn projection + discrete-alpha blend + pos emb -> xs
  proj_rows<SD>(bufA, pw, lane, wid, acc);
  {
    float pbv = pbias[lane];
#pragma unroll
    for (int ir = 0; ir < RPW; ++ir) {
      int s = wid + NW * ir;
      if (s < SS) {
        float g = acc[ir] + pbv;
        size_t base = (size_t)sidx[s] * SD + lane;
        xs[s * PX + lane] = alpha * bert[base] + one_m_alpha * g + pos[s * SD + lane];
      }
    }
  }
  __syncthreads();

  const float inv_sqrt_dh = 0.17677669529663687f;  // 1/sqrt(32)

#pragma unroll 1
  for (int blk = 0; blk < NBLK; ++blk) {
    const float* Wq = wq + blk * SD * SD;
    const float* Wk = wk + blk * SD * SD;
    const float* Wv = wv + blk * SD * SD;
    const float* Wo = wo + blk * SD * SD;
    const float* W1 = w1 + blk * SD * DFF;
    const float* B1 = b1 + blk * DFF;
    const float* W2 = w2 + blk * DFF * SD;
    const float* B2 = b2 + blk * SD;

    // ---- Q -> bufA (p68)
    proj_rows<SD>(xs, Wq, lane, wid, acc);
#pragma unroll
    for (int ir = 0; ir < RPW; ++ir) {
      int s = wid + NW * ir;
      if (s < SS) bufA[s * PX + lane] = acc[ir];
    }
    // ---- K^T -> bufB (p65, transposed write, conflict-free)
    proj_rows<SD>(xs, Wk, lane, wid, acc);
#pragma unroll
    for (int ir = 0; ir < RPW; ++ir) {
      int s = wid + NW * ir;
      if (s < SS) bufB[lane * PK + s] = acc[ir];
    }
    __syncthreads();

    // ---- scores: wave rows = sq, lane = sk. K column in registers,
    //      reused across the wave's query rows.
    {
      const int sk = lane;
      const bool skv = (sk < SS);
      const bool kmask = skv && (sidx[sk] != 0);
#pragma unroll 1
      for (int h = 0; h < 2; ++h) {
        float kr[32];
#pragma unroll
        for (int dh = 0; dh < 32; ++dh) kr[dh] = bufB[(h * 32 + dh) * PK + sk];
#pragma unroll
        for (int ir = 0; ir < RPW; ++ir) {
          int sq = wid + NW * ir;
          if (sq < SS) {
            float ax = 0.f, ay = 0.f, az = 0.f, aw = 0.f;
#pragma unroll
            for (int j = 0; j < 8; ++j) {
              float4 qv = *(const float4*)&bufA[sq * PX + h * 32 + 4 * j];
              ax += qv.x * kr[4 * j + 0];
              ay += qv.y * kr[4 * j + 1];
              az += qv.z * kr[4 * j + 2];
              aw += qv.w * kr[4 * j + 3];
            }
            float sc = ((ax + ay) + (az + aw)) * inv_sqrt_dh;
            if (skv) scw[(h * SS + sq) * 52 + sk] = kmask ? sc : -1e9f;
          }
        }
      }
    }
    __syncthreads();

    // ---- softmax: wave per (h,sq) row, lane = sk; rows in independent pairs
    {
      int r = wid;
#pragma unroll 1
      for (; r + NW < 2 * SS; r += 2 * NW) {
        float v0 = (lane < SS) ? scw[r * 52 + lane] : -1e30f;
        float v1 = (lane < SS) ? scw[(r + NW) * 52 + lane] : -1e30f;
        float m0 = v0, m1 = v1;
#pragma unroll
        for (int o = 32; o > 0; o >>= 1) {
          m0 = fmaxf(m0, __shfl_xor(m0, o, 64));
          m1 = fmaxf(m1, __shfl_xor(m1, o, 64));
        }
        float e0 = (lane < SS) ? __expf(v0 - m0) : 0.f;
        float e1 = (lane < SS) ? __expf(v1 - m1) : 0.f;
        float2 sm = wred_sum2(e0, e1);
        if (lane < 52) {
          scw[r * 52 + lane] = e0 / sm.x;        // cols 50,51 zeroed for f4 ctx
          scw[(r + NW) * 52 + lane] = e1 / sm.y;
        }
      }
      if (r < 2 * SS) {
        float v = (lane < SS) ? scw[r * 52 + lane] : -1e30f;
        float mx = v;
#pragma unroll
        for (int o = 32; o > 0; o >>= 1) mx = fmaxf(mx, __shfl_xor(mx, o, 64));
        float e = (lane < SS) ? __expf(v - mx) : 0.f;
        float sm = wred_sum(e);
        if (lane < 52) scw[r * 52 + lane] = e / sm;
      }
    }
    __syncthreads();

    // ---- V -> bufA (p65; overwrites consumed Q)
    proj_rows<SD>(xs, Wv, lane, wid, acc);
#pragma unroll
    for (int ir = 0; ir < RPW; ++ir) {
      int s = wid + NW * ir;
      if (s < SS) bufA[s * PK + lane] = acc[ir];
    }
    __syncthreads();

    // ---- ctx = attn @ V -> bufB (p68; overwrites consumed K^T).
    //      attn cols 50,51 are exact zeros; stale v-rows 50,51 are finite.
#pragma unroll
    for (int ir = 0; ir < RPW; ++ir) {
      int sq = wid + NW * ir;
      if (sq < SS) {
        const int hb = (lane >> 5) * SS * 52;
        float ax = 0.f, ay = 0.f, az = 0.f, aw = 0.f;
#pragma unroll
        for (int j = 0; j < 13; ++j) {
          float4 av = *(const float4*)&scw[hb + sq * 52 + 4 * j];
          ax += av.x * bufA[(4 * j + 0) * PK + lane];
          ay += av.y * bufA[(4 * j + 1) * PK + lane];
          az += av.z * bufA[(4 * j + 2) * PK + lane];
          aw += av.w * bufA[(4 * j + 3) * PK + lane];
        }
        bufB[sq * PX + lane] = (ax + ay) + (az + aw);
      }
    }
    __syncthreads();

    // ---- O-projection + residual + LN1 -> xs
    proj_rows<SD>(bufB, Wo, lane, wid, acc);
    {
      float gv = ln1g[blk * SD + lane], bv = ln1b[blk * SD + lane];
#pragma unroll
      for (int ir = 0; ir < RPW; ++ir) {
        int s = wid + NW * ir;
        if (s < SS) {
          float val = xs[s * PX + lane] + acc[ir];
          float2 ss = wred_sum2(val, val * val);
          float m = ss.x * (1.f / 64);
          float var = fmaxf(ss.y * (1.f / 64) - m * m, 0.f);
          float rs = rsqrtf(var + 1e-5f);
          xs[s * PX + lane] = (val - m) * rs * gv + bv;
        }
      }
    }
    __syncthreads();

    // ---- FFN: 4 chunks of 64 hidden dims; h staged in bufA, out accumulated
    //      in registers across chunks.
    float acc2[RPW];
#pragma unroll
    for (int ir = 0; ir < RPW; ++ir) acc2[ir] = 0.f;
#pragma unroll 1
    for (int c = 0; c < 4; ++c) {
      // W1 chunk: columns c*64+lane, rows 0..63
      proj_rows<DFF>(xs, W1 + c * 64, lane, wid, acc);
      float b1v = B1[c * 64 + lane];
#pragma unroll
      for (int ir = 0; ir < RPW; ++ir) {
        int s = wid + NW * ir;
        if (s < SS) bufA[s * PX + lane] = gelu_tanh(acc[ir] + b1v);
      }
      __syncthreads();
      // W2 chunk: rows c*64..c*64+63, column lane
      proj_rows<SD>(bufA, W2 + c * 64 * SD, lane, wid, acc);
#pragma unroll
      for (int ir = 0; ir < RPW; ++ir) acc2[ir] += acc[ir];
      __syncthreads();
    }

    // ---- residual + LN2 -> xs
    {
      float gv = ln2g[blk * SD + lane], bv = ln2b[blk * SD + lane];
      float b2v = B2[lane];
#pragma unroll
      for (int ir = 0; ir < RPW; ++ir) {
        int s = wid + NW * ir;
        if (s < SS) {
          float val = xs[s * PX + lane] + acc2[ir] + b2v;
          float2 ss = wred_sum2(val, val * val);
          float m = ss.x * (1.f / 64);
          float var = fmaxf(ss.y * (1.f / 64) - m * m, 0.f);
          float rs = rsqrtf(var + 1e-5f);
          xs[s * PX + lane] = (val - m) * rs * gv + bv;
        }
      }
    }
    __syncthreads();
  }

  // ---- final LN + gather row (lengths-1)
  if (wid == 0) {
    int sl = len - 1;
    float val = xs[sl * PX + lane];
    float2 ss = wred_sum2(val, val * val);
    float m = ss.x * (1.f / 64);
    float var = fmaxf(ss.y * (1.f / 64) - m * m, 0.f);
    float rs = rsqrtf(var + 1e-5f);
    out[b * SD + lane] = (val - m) * rs * lnfg[lane] + lnfb[lane];
  }
}

// ---------------------------------------------------------------------------
extern "C" void kernel_launch(void* const* d_in, const int* in_sizes, int n_in,
                              void* d_out, int out_size, void* d_ws, size_t ws_size,
                              hipStream_t stream) {
  const int*   seq   = (const int*)d_in[0];
  const int*   lens  = (const int*)d_in[1];
  const int*   ei    = (const int*)d_in[2];
  const float* ew    = (const float*)d_in[3];
  const float* bert  = (const float*)d_in[4];
  const float* gnn   = (const float*)d_in[5];
  const float* pw    = (const float*)d_in[6];
  const float* pb    = (const float*)d_in[7];
  const float* pos   = (const float*)d_in[8];
  const float* wq    = (const float*)d_in[9];
  const float* wk    = (const float*)d_in[10];
  const float* wv    = (const float*)d_in[11];
  const float* wo    = (const float*)d_in[12];
  const float* w1    = (const float*)d_in[13];
  const float* b1    = (const float*)d_in[14];
  const float* w2    = (const float*)d_in[15];
  const float* b2    = (const float*)d_in[16];
  const float* ln1g  = (const float*)d_in[17];
  const float* ln1b  = (const float*)d_in[18];
  const float* ln2g  = (const float*)d_in[19];
  const float* ln2b  = (const float*)d_in[20];
  const float* lnfg  = (const float*)d_in[21];
  const float* lnfb  = (const float*)d_in[22];
  float* out = (float*)d_out;

  const int E = in_sizes[2] / 2;          // 1,000,000
  const int B = in_sizes[0] / SS;         // 1024
  const int N = in_sizes[4] / SD;         // 100,001

  const int*   esrc = ei;
  const int*   edst = ei + E;

  // ---- workspace layout
  float* g1x = (float*)d_ws;                       // N x 64
  float* g2x = g1x + (size_t)N * SD;               // N x 64
  const int NCH = (N + 1023) >> 10;                // scan chunks of 1024
  const int PADN = NCH << 10;                      // padded count array size
  int*   cnt  = (int*)(g2x + (size_t)N * SD);      // PADN
  int*   bsum = cnt + PADN;                        // NCH (<=128)
  int*   rp   = bsum + 128;                        // N+1
  int*   wp   = rp + (N + 1);                      // N
  int*   es   = wp + N;                            // E
  float* ewt  = (float*)(es + E);                  // E
  size_t need = (size_t)((char*)(ewt + E) - (char*)d_ws);

  if (ws_size >= need && NCH <= 128) {
    // ---- CSR build + gather (no atomics in the heavy passes)
    hipMemsetAsync(cnt, 0, (size_t)PADN * sizeof(int), stream);
    const int gb = (E + 255) / 256;
    gnn_hist<<<gb, 256, 0, stream>>>(edst, cnt, E);
    gnn_chunk_sums<<<NCH, 256, 0, stream>>>(cnt, bsum);
    gnn_scan_bsum<<<1, 128, 0, stream>>>(bsum, NCH);
    gnn_chunk_scan<<<NCH, 256, 0, stream>>>(cnt, bsum, rp, wp, N);
    gnn_build<<<gb, 256, 0, stream>>>(esrc, edst, ew, wp, es, ewt, E);
    const int nb = (N + 3) / 4;
    gnn_gather<<<nb, 256, 0, stream>>>(gnn, rp, es, ewt, g1x, N);
    gnn_gather<<<nb, 256, 0, stream>>>(g1x, rp, es, ewt, g2x, N);
  } else {
    // ---- fallback: atomic scatter
    hipMemsetAsync(g1x, 0, (size_t)2 * N * SD * sizeof(float), stream);
    const long total = (long)E * 64;
    const int sblocks = (int)((total + 255) / 256);
    gnn_scatter<<<sblocks, 256, 0, stream>>>(gnn, esrc, edst, ew, g1x, E);
    gnn_scatter<<<sblocks, 256, 0, stream>>>(g1x, esrc, edst, ew, g2x, E);
  }

  seq_transformer<<<B, 512, 0, stream>>>(
      seq, lens, bert, gnn, g1x, g2x, pw, pb, pos,
      wq, wk, wv, wo, w1, b1, w2, b2,
      ln1g, ln1b, ln2g, ln2b, lnfg, lnfb, out);
}